// Round 12
// baseline (584.643 us; speedup 1.0000x reference)
//
#include <hip/hip_runtime.h>
#include <stdint.h>

#define L 2048
#define DMODEL 2048
#define NH 16

typedef __bf16 bf16x8 __attribute__((ext_vector_type(8)));
typedef float f32x4 __attribute__((ext_vector_type(4)));
typedef short s16x4 __attribute__((ext_vector_type(4)));

__device__ __forceinline__ unsigned short f2bf(float f) {
    union { float f; unsigned int i; } w; w.f = f;
    unsigned int u = w.i;
    unsigned int r = u + 0x7fffu + ((u >> 16) & 1u);
    return (unsigned short)(r >> 16);
}

// Async global->LDS, 16 bytes per lane.  LDS dest is wave-uniform base +
// lane*16 (m104); swizzled layouts are achieved by pre-swizzling the GLOBAL
// source address (rule 21: both-sides involution).
__device__ __forceinline__ void gload_lds16(const unsigned short* g, unsigned short* l) {
    __builtin_amdgcn_global_load_lds(
        (const __attribute__((address_space(1))) void*)g,
        (__attribute__((address_space(3))) void*)l, 16, 0, 0);
}

// ---------------------------------------------------------------------------
// Tiled bf16-MFMA GEMM, C = alpha * A (MxK) * B'(NxK)^T.  2-phase pipeline,
// double-buffered LDS, one __syncthreads per K-step.  LDS k-slot XOR-swizzle
// (rule 21).  CMODE 0/1/2 as before; CMODE 3 = fused QKV epilogue.
// SWZ 1: QKV 768 blocks (z -> XCD z&7); SWZ 3: proj 512 blocks (bx -> XCD).
// ---------------------------------------------------------------------------
template<int CMODE, int BM, int BK, int SWZ>
__global__ __launch_bounds__(256, 2)
void gemm_bt(const unsigned short* __restrict__ Ag,
             const unsigned short* __restrict__ B,
             void* __restrict__ C,
             int K, int lda, int ldb, int ldc,
             long long sA, long long sB, long long sC, float alpha)
{
    constexpr int KC8 = BK / 8;            // 16B slots per row
    constexpr int SWM = (KC8 >= 8) ? 7 : (KC8 - 1);
    constexpr int CA  = BM * BK / 2048;    // A chunks per thread
    constexpr int CB  = BK / 16;           // B chunks per thread (BN=128)
    constexpr int MFR = BM / 32;           // m-fragments per wave
    constexpr int KG  = BK / 32;           // MFMA K-groups per step

    __shared__ unsigned short As[2][BM * BK];
    __shared__ unsigned short Bs[2][128 * BK];

    int bx, by, bz;
    if constexpr (SWZ == 1) {            // QKV: 768 blocks
        const int xcd = blockIdx.x & 7, rest = blockIdx.x >> 3;  // rest<96
        bx = 0; by = rest & 15; bz = xcd + 8 * (rest >> 4);
    } else if constexpr (SWZ == 3) {     // proj: 512 blocks
        const int xcd = blockIdx.x & 7, rest = blockIdx.x >> 3;  // rest<64
        bx = xcd + 8 * (rest >> 5); by = rest & 31; bz = 0;
    } else {
        bx = blockIdx.x; by = blockIdx.y; bz = blockIdx.z;
    }

    const int tid  = threadIdx.x;
    const int wave = tid >> 6;
    const int lane = tid & 63;
    const int quad = lane >> 4;
    const int l16  = lane & 15;

    const int tileN = bx * 128;
    const int tileM = by * BM;

    const long long zA = (CMODE == 3) ? (long long)(bz >> 4) : (long long)bz;
    const unsigned short* A16 = Ag + zA * sA;
    B += (long long)bz * sB;

    const int wm = (wave >> 1) * (BM / 2);
    const int wn = (wave & 1) * 64;

    auto stageB = [&](int kk, int buf) {
        #pragma unroll
        for (int j = 0; j < CB; ++j) {
            const int ch = tid + j * 256;
            const int rb = ch / KC8, sl = (ch % KC8) ^ (rb & SWM);
            gload_lds16(B + (long long)(tileN + rb) * ldb + (kk + sl * 8), &Bs[buf][ch * 8]);
        }
    };
    auto stageA = [&](int kk, int buf) {
        #pragma unroll
        for (int j = 0; j < CA; ++j) {
            const int ch = tid + j * 256;
            const int ra = ch / KC8, sl = (ch % KC8) ^ (ra & SWM);
            gload_lds16(A16 + (long long)(tileM + ra) * lda + (kk + sl * 8), &As[buf][ch * 8]);
        }
    };

    f32x4 acc[MFR][4] = {};
    const int nt = K / BK;

    stageA(0, 0);
    stageB(0, 0);
    __syncthreads();

    int cur = 0;
    for (int t = 0; t < nt; ++t) {
        const int nxt = cur ^ 1;
        const int k0n = (t + 1) * BK;
        if (t + 1 < nt) { stageA(k0n, nxt); stageB(k0n, nxt); }

        bf16x8 af[MFR][KG], bfr[4][KG];
        #pragma unroll
        for (int i = 0; i < MFR; ++i) {
            const int rr = wm + i * 16 + l16;
            #pragma unroll
            for (int g = 0; g < KG; ++g)
                af[i][g] = *(const bf16x8*)(&As[cur][rr * BK + ((g * 32 + quad * 8) ^ ((rr & SWM) << 3))]);
        }
        #pragma unroll
        for (int j = 0; j < 4; ++j) {
            const int rr = wn + j * 16 + l16;
            #pragma unroll
            for (int g = 0; g < KG; ++g)
                bfr[j][g] = *(const bf16x8*)(&Bs[cur][rr * BK + ((g * 32 + quad * 8) ^ ((rr & SWM) << 3))]);
        }
        #pragma unroll
        for (int g = 0; g < KG; ++g)
            #pragma unroll
            for (int i = 0; i < MFR; ++i)
                #pragma unroll
                for (int j = 0; j < 4; ++j)
                    acc[i][j] = __builtin_amdgcn_mfma_f32_16x16x32_bf16(af[i][g], bfr[j][g], acc[i][j], 0, 0, 0);

        __syncthreads();
        cur = nxt;
    }

    // Epilogue.  D layout: col = lane&15, row = quad*4+reg  [m89-verified]
    const long long cb = (long long)bz * sC;
    const float aEff = (CMODE == 3) ? (bz < 16 ? alpha : 1.0f) : alpha;
    #pragma unroll
    for (int i = 0; i < MFR; ++i) {
        const int r0 = tileM + wm + i * 16 + quad * 4;
        #pragma unroll
        for (int j = 0; j < 4; ++j) {
            const int c = tileN + wn + j * 16 + l16;
            f32x4 d = acc[i][j];
            if (CMODE == 0) {
                unsigned short* Cp = (unsigned short*)C + cb;
                #pragma unroll
                for (int r = 0; r < 4; ++r)
                    Cp[(long long)(r0 + r) * ldc + c] = f2bf(d[r] * aEff);
            } else if (CMODE == 1) {
                unsigned short* Cp = (unsigned short*)C + cb + (long long)c * ldc + r0;
                s16x4 pk;
                #pragma unroll
                for (int r = 0; r < 4; ++r) pk[r] = (short)f2bf(d[r] * aEff);
                *(s16x4*)Cp = pk;
            } else if (CMODE == 2) {
                float* Cp = (float*)C + cb;
                #pragma unroll
                for (int r = 0; r < 4; ++r)
                    Cp[(long long)(r0 + r) * ldc + c] = d[r] * aEff;
            } else { // CMODE 3: fused QKV
                if (bz < 32) {                  // qh/kh, bf16 row-major, ldc=128
                    unsigned short* Cp = (unsigned short*)C + cb;
                    #pragma unroll
                    for (int r = 0; r < 4; ++r)
                        Cp[(long long)(r0 + r) * 128 + c] = f2bf(d[r] * aEff);
                } else {                         // vhT, bf16 transposed, ldc=2048
                    unsigned short* Cp = (unsigned short*)C + cb + (long long)c * 2048 + r0;
                    s16x4 pk;
                    #pragma unroll
                    for (int r = 0; r < 4; ++r) pk[r] = (short)f2bf(d[r]);
                    *(s16x4*)Cp = pk;
                }
            }
        }
    }
}

// ---------------------------------------------------------------------------
// stats: S = qh[h] @ kh[h]^T per 128x128 tile, K=128 single-shot (one stage,
// one barrier).  No C write; atomicAdd per-column exp-sums (no-max softmax,
// fp32-safe).  Grid 4096 linear, head -> XCD h&7.  LDS 64KB, 2 blocks/CU.
// ---------------------------------------------------------------------------
__global__ __launch_bounds__(256, 2)
void stats_qk(const unsigned short* __restrict__ qh,
              const unsigned short* __restrict__ kh,
              float* __restrict__ sums)
{
    __shared__ unsigned short As[128 * 128];
    __shared__ unsigned short Bs[128 * 128];

    const int xcd = blockIdx.x & 7, rest = blockIdx.x >> 3;  // rest<512
    const int inner = rest & 255;
    const int bx = inner & 15, by = inner >> 4;
    const int bz = xcd + 8 * (rest >> 8);

    const int tid = threadIdx.x;
    const int wave = tid >> 6, lane = tid & 63, quad = lane >> 4, l16 = lane & 15;
    const int tileN = bx * 128, tileM = by * 128;
    const int wm = (wave >> 1) * 64, wn = (wave & 1) * 64;

    const unsigned short* A16 = qh + (long long)bz * 262144;
    const unsigned short* B16 = kh + (long long)bz * 262144;

    #pragma unroll
    for (int j = 0; j < 8; ++j) {          // 2048 chunks per tile, 8/thread
        const int ch = tid + j * 256;
        const int rr = ch >> 4, sl = (ch & 15) ^ (rr & 7);
        gload_lds16(A16 + (long long)(tileM + rr) * 128 + sl * 8, &As[ch * 8]);
        gload_lds16(B16 + (long long)(tileN + rr) * 128 + sl * 8, &Bs[ch * 8]);
    }
    __syncthreads();

    f32x4 acc[4][4] = {};
    #pragma unroll
    for (int g = 0; g < 4; ++g) {
        bf16x8 af[4], bfr[4];
        #pragma unroll
        for (int i = 0; i < 4; ++i) {
            const int rr = wm + i * 16 + l16;
            af[i] = *(const bf16x8*)(&As[rr * 128 + ((g * 32 + quad * 8) ^ ((rr & 7) << 3))]);
        }
        #pragma unroll
        for (int j = 0; j < 4; ++j) {
            const int rr = wn + j * 16 + l16;
            bfr[j] = *(const bf16x8*)(&Bs[rr * 128 + ((g * 32 + quad * 8) ^ ((rr & 7) << 3))]);
        }
        #pragma unroll
        for (int i = 0; i < 4; ++i)
            #pragma unroll
            for (int j = 0; j < 4; ++j)
                acc[i][j] = __builtin_amdgcn_mfma_f32_16x16x32_bf16(af[i], bfr[j], acc[i][j], 0, 0, 0);
    }

    // column exp-sums: butterfly over quads (rows), one atomic per col per wave
    float* sc = sums + (long long)bz * 2048;
    #pragma unroll
    for (int j = 0; j < 4; ++j) {
        float ej = 0.f;
        #pragma unroll
        for (int i = 0; i < 4; ++i)
            #pragma unroll
            for (int r = 0; r < 4; ++r) ej += __expf(acc[i][j][r]);
        ej += __shfl_xor(ej, 16, 64);
        ej += __shfl_xor(ej, 32, 64);
        if (quad == 0)
            atomicAdd(&sc[tileN + wn + j * 16 + l16], ej);
    }
}

// ---------------------------------------------------------------------------
// Fused scores+softmax+PV.  Grid 512 linear = 8 XCD x (32 qt x 2 hi).
// Block 256 (4 waves); per block q rows [qt*64,+64), head h.
// qh fragments loop-invariant in 64 VGPR (loaded once from global).
//
// COUNTED-VMCNT PIPELINE (T4, distance-2 prefetch, kh/vh TRIPLE-buffered):
//   bar1(t) = s_waitcnt vmcnt(4) + raw s_barrier.  Per-thread vmem issue
//     order makes the newest 4 ops kv(t+1)'s stage loads (NT stores and sums
//     loads audited for prologue/steady/tail), so vmcnt(4) retires exactly
//     tile t's kv; kv(t+1)/kv(t+2) stay IN FLIGHT across the barrier (the
//     old __syncthreads drained them -- the m233 stall).
//   bar2(t) = s_waitcnt lgkmcnt(0) + raw s_barrier: p16 ds_writes visible,
//     kv loads untouched.
//   Race audit: stage(t+2) targets buf (t-1)%3 whose last reads (S/PV of
//   iter t-1) retire before any wave passes bar1(t); p16[t&1] rotation is
//   safe under barrier convergence.  sched_barrier(0) pins compiler motion
//   (rule 18).  LDS 56KB -> 2 blocks/CU.
// ---------------------------------------------------------------------------
__global__ __launch_bounds__(256, 2)
void fused_pv(const unsigned short* __restrict__ qh,
              const unsigned short* __restrict__ kh,
              const unsigned short* __restrict__ vhT,
              const float* __restrict__ sums,
              float* __restrict__ attn, unsigned short* __restrict__ O)
{
    __shared__ unsigned short kh_s[3][32 * 128];
    __shared__ unsigned short vh_s[3][128 * 32];
    __shared__ unsigned short p16[2][64 * 32];

    const int tid = threadIdx.x;
    const int wave = tid >> 6, lane = tid & 63, quad = lane >> 4, l16 = lane & 15;
    const int slot = blockIdx.x >> 3;
    const int qt = slot & 31;
    const int h  = (blockIdx.x & 7) + 8 * (slot >> 5);
    const int wA = wave >> 1, wB = wave & 1;   // S:  wA=key-half(16), wB=q-half(32)
                                               // PV: wA=q-half(32),   wB=vd-half(64)
    const unsigned short* qg = qh + (long long)h * 262144 + (long long)qt * 64 * 128;
    const unsigned short* kg = kh + (long long)h * 262144;
    const unsigned short* vg = vhT + (long long)h * 262144;
    const float* smp = sums + h * 2048;
    float* ap = attn + (long long)h * L * L + (long long)qt * 64 * 2048;

    auto stage_kv = [&](int kt, int b_) {
        #pragma unroll
        for (int jj = 0; jj < 2; ++jj) {       // kh tile: 32 rows x 128 dk = 512 chunks
            const int c = tid + jj * 256;
            const int rl = c >> 4, sl = (c & 15) ^ (rl & 7);
            gload_lds16(kg + (long long)(kt * 32 + rl) * 128 + sl * 8, &kh_s[b_][c * 8]);
        }
        #pragma unroll
        for (int jj = 0; jj < 2; ++jj) {       // vh tile: 128 vd x 32 keys = 512 chunks
            const int c = tid + jj * 256;
            const int vd = c >> 2, sl = (c & 3) ^ (vd & 3);
            gload_lds16(vg + (long long)vd * 2048 + kt * 32 + sl * 8, &vh_s[b_][c * 8]);
        }
    };

    // prologue: qh fragments straight into registers (loop-invariant),
    // then kv tiles 0 and 1.  No syncthreads: bar1(0) covers it.
    bf16x8 bq[2][4];
    #pragma unroll
    for (int j = 0; j < 2; ++j) {
        const int q = wB * 32 + j * 16 + l16;
        #pragma unroll
        for (int g = 0; g < 4; ++g)
            bq[j][g] = *(const bf16x8*)(qg + (long long)q * 128 + g * 32 + quad * 8);
    }
    stage_kv(0, 0);
    stage_kv(1, 1);

    f32x4 acc_o[2][4] = {};
    const int krow = wA * 16 + l16;            // S A-operand row (key, local)

    for (int t = 0; t < 64; ++t) {
        // bar1: tile-t kv retired per-wave, kv(t+1)+ stay in flight.
        asm volatile("s_waitcnt vmcnt(4)" ::: "memory");
        __builtin_amdgcn_s_barrier();
        __builtin_amdgcn_sched_barrier(0);

        const int b3 = t % 3;
        const int cb = t & 1;
        const int kb = t * 32 + wA * 16 + quad * 4;
        const f32x4 sg4 = *(const f32x4*)(smp + kb);   // L2-hot 128KB table

        // S^T(t): A=kh (M=key 32), B=bq regs.  8 MFMA/wave.
        bf16x8 af[4];
        #pragma unroll
        for (int g = 0; g < 4; ++g)
            af[g] = *(const bf16x8*)(&kh_s[b3][krow * 128 + ((g * 32 + quad * 8) ^ ((krow & 7) << 3))]);
        f32x4 acc_s[2];
        __builtin_amdgcn_s_setprio(1);
        #pragma unroll
        for (int j = 0; j < 2; ++j) {
            f32x4 s = {};
            #pragma unroll
            for (int g = 0; g < 4; ++g)
                s = __builtin_amdgcn_mfma_f32_16x16x32_bf16(af[g], bq[j][g], s, 0, 0, 0);
            acc_s[j] = s;
        }
        __builtin_amdgcn_s_setprio(0);

        // distance-2 prefetch into buf (t+2)%3 == (t-1)%3 (dead since bar1).
        if (t + 2 < 64) stage_kv(t + 2, (t + 2) % 3);

        // normalize (p = exp(s) * 1/sum) + NT attn write + p16 pack.
        // D: row(key)=quad*4+r, col(q)=l16.
        f32x4 il4;
        #pragma unroll
        for (int r = 0; r < 4; ++r) il4[r] = __builtin_amdgcn_rcpf(sg4[r]);
        #pragma unroll
        for (int j = 0; j < 2; ++j) {
            const int q = wB * 32 + j * 16 + l16;
            f32x4 p;
            #pragma unroll
            for (int r = 0; r < 4; ++r)
                p[r] = __expf(acc_s[j][r]) * il4[r];
            __builtin_nontemporal_store(p, (f32x4*)(ap + (long long)q * 2048 + kb));
            s16x4 pk;
            #pragma unroll
            for (int r = 0; r < 4; ++r) pk[r] = (short)f2bf(p[r]);
            *(s16x4*)(&p16[cb][q * 32 + ((wA * 16 + quad * 4) ^ ((q & 3) << 3))]) = pk;
        }

        // bar2: p16 visible; kv stage loads stay in flight (no vmcnt).
        asm volatile("s_waitcnt lgkmcnt(0)" ::: "memory");
        __builtin_amdgcn_s_barrier();
        __builtin_amdgcn_sched_barrier(0);

        // PV(t): P (64q x 32k) @ vh^T.  8 MFMA/wave.
        bf16x8 pa[2], vb[4];
        #pragma unroll
        for (int i = 0; i < 2; ++i) {
            const int qq = wA * 32 + i * 16 + l16;
            pa[i] = *(const bf16x8*)(&p16[cb][qq * 32 + ((quad * 8) ^ ((qq & 3) << 3))]);
        }
        #pragma unroll
        for (int j = 0; j < 4; ++j) {
            const int vd = wB * 64 + j * 16 + l16;
            vb[j] = *(const bf16x8*)(&vh_s[b3][vd * 32 + ((quad * 8) ^ ((vd & 3) << 3))]);
        }
        __builtin_amdgcn_s_setprio(1);
        #pragma unroll
        for (int i = 0; i < 2; ++i)
            #pragma unroll
            for (int j = 0; j < 4; ++j)
                acc_o[i][j] = __builtin_amdgcn_mfma_f32_16x16x32_bf16(pa[i], vb[j], acc_o[i][j], 0, 0, 0);
        __builtin_amdgcn_s_setprio(0);
    }

    // O epilogue: O[q][h*128+vd] bf16.  D: row(q)=quad*4+r, col(vd)=l16.
    #pragma unroll
    for (int i = 0; i < 2; ++i) {
        const int q = qt * 64 + wA * 32 + i * 16 + quad * 4;
        #pragma unroll
        for (int j = 0; j < 4; ++j) {
            const int vd = h * 128 + wB * 64 + j * 16 + l16;
            #pragma unroll
            for (int r = 0; r < 4; ++r)
                O[(long long)(q + r) * 2048 + vd] = f2bf(acc_o[i][j][r]);
        }
    }
}

// ---------------------------------------------------------------------------
// prep: merged stage-0 (3 launches -> 1).  Flat grid 18464 x 256:
//   [0, 6144):       q,k,v fp32 -> bf16  (z = bid/2048, 8 elems/thread)
//   [6144, 18432):   Wq/Wk/Wv transpose+cvt (48 heads x 4x64 32-tiles)
//   [18432, 18464):  zero the exp-sums table (32K floats)
// ---------------------------------------------------------------------------
__global__ __launch_bounds__(256)
void prep(const float* __restrict__ q, const float* __restrict__ k,
          const float* __restrict__ v,
          const float* __restrict__ Wq, const float* __restrict__ Wk,
          const float* __restrict__ Wv,
          unsigned short* __restrict__ qkvb, unsigned short* __restrict__ WT,
          float* __restrict__ sums)
{
    __shared__ float t[32][33];
    const int bid = blockIdx.x;
    const int tid = threadIdx.x;

    if (bid < 6144) {                      // ---- cvt q,k,v ----
        const int z = bid >> 11, xb = bid & 2047;
        const float* in = z == 0 ? q : z == 1 ? k : v;
        const long long i = ((long long)xb * 256 + tid) * 8;
        const float4 f0 = *(const float4*)(in + i);
        const float4 f1 = *(const float4*)(in + i + 4);
        union { int4 v4; unsigned short u[8]; } tt;
        tt.u[0] = f2bf(f0.x); tt.u[1] = f2bf(f0.y); tt.u[2] = f2bf(f0.z); tt.u[3] = f2bf(f0.w);
        tt.u[4] = f2bf(f1.x); tt.u[5] = f2bf(f1.y); tt.u[6] = f2bf(f1.z); tt.u[7] = f2bf(f1.w);
        *(int4*)(qkvb + (long long)z * 4194304 + i) = tt.v4;
    } else if (bid < 18432) {              // ---- weight transpose ----
        const int r = bid - 6144;
        const int z = r >> 8, rr = r & 255;
        const int bx = rr & 3, by = rr >> 2;
        const int widx = z >> 4, hh = z & 15;
        const float* in = (widx == 0 ? Wq : widx == 1 ? Wk : Wv) + (long long)hh * 2048 * 128;
        unsigned short* o = WT + (long long)z * 262144;
        const int c0 = bx * 32, r0 = by * 32;
        const int tx = tid & 31, ty0 = tid >> 5;
        #pragma unroll
        for (int jj = 0; jj < 4; ++jj) {
            const int j = ty0 + jj * 8;
            t[j][tx] = in[(long long)(r0 + j) * 128 + (c0 + tx)];
        }
        __syncthreads();
        #pragma unroll
        for (int jj = 0; jj < 4; ++jj) {
            const int j = ty0 + jj * 8;
            o[(long long)(c0 + j) * 2048 + (r0 + tx)] = f2bf(t[tx][j]);
        }
    } else {                               // ---- zero sums ----
        const int bt = bid - 18432;
        float4 zz = {0.f, 0.f, 0.f, 0.f};
        ((float4*)sums)[bt * 256 + tid] = zz;
    }
}

// ---------------------------------------------------------------------------
// 32x32 tile transpose, fp32 in -> bf16 out. Block (32,8).  (Pw only.)
// ---------------------------------------------------------------------------
__global__ __launch_bounds__(256)
void transpose_f2b(const float* __restrict__ in, unsigned short* __restrict__ out,
                   int rows, int cols)
{
    __shared__ float t[32][33];
    const long long base = (long long)blockIdx.z * rows * cols;
    const int c0 = blockIdx.x * 32, r0 = blockIdx.y * 32;
    const int tx = threadIdx.x, ty0 = threadIdx.y;
    #pragma unroll
    for (int jj = 0; jj < 4; ++jj) {
        const int j = ty0 + jj * 8;
        t[j][tx] = in[base + (long long)(r0 + j) * cols + (c0 + tx)];
    }
    __syncthreads();
    #pragma unroll
    for (int jj = 0; jj < 4; ++jj) {
        const int j = ty0 + jj * 8;
        out[base + (long long)(c0 + j) * rows + (r0 + tx)] = f2bf(t[tx][j]);
    }
}

// ---------------------------------------------------------------------------
// Residual + bias + LayerNorm (all fp32), one block (256 thr) per row of 2048.
// ---------------------------------------------------------------------------
__global__ __launch_bounds__(256)
void ln_resid(const float* __restrict__ ypre, const float* __restrict__ resid,
              const float* __restrict__ pb, const float* __restrict__ g,
              const float* __restrict__ bta, float* __restrict__ y)
{
    __shared__ float as_[4], as2_[4];
    const int l = blockIdx.x;
    const int tid = threadIdx.x;
    float v[8]; float s = 0.f, s2 = 0.f;
    #pragma unroll
    for (int i = 0; i < 8; ++i) {
        const int d = tid + i * 256;
        float t = ypre[(long long)l * DMODEL + d] + pb[d] + resid[(long long)l * DMODEL + d];
        v[i] = t; s += t; s2 += t * t;
    }
    #pragma unroll
    for (int off = 32; off > 0; off >>= 1) {
        s  += __shfl_down(s, off, 64);
        s2 += __shfl_down(s2, off, 64);
    }
    const int wave = tid >> 6, lane = tid & 63;
    if (lane == 0) { as_[wave] = s; as2_[wave] = s2; }
    __syncthreads();
    const float S  = as_[0] + as_[1] + as_[2] + as_[3];
    const float S2 = as2_[0] + as2_[1] + as2_[2] + as2_[3];
    const float mu  = S * (1.0f / DMODEL);
    const float var = S2 * (1.0f / DMODEL) - mu * mu;
    const float rs  = rsqrtf(var + 1e-5f);
    #pragma unroll
    for (int i = 0; i < 8; ++i) {
        const int d = tid + i * 256;
        y[(long long)l * DMODEL + d] = (v[i] - mu) * rs * g[d] + bta[d];
    }
}

// ---------------------------------------------------------------------------
extern "C" void kernel_launch(void* const* d_in, const int* in_sizes, int n_in,
                              void* d_out, int out_size, void* d_ws, size_t ws_size,
                              hipStream_t stream)
{
    const float* q  = (const float*)d_in[0];
    const float* k  = (const float*)d_in[1];
    const float* v  = (const float*)d_in[2];
    const float* Wq = (const float*)d_in[3];
    const float* Wk = (const float*)d_in[4];
    const float* Wv = (const float*)d_in[5];
    const float* Pw = (const float*)d_in[6];
    const float* Pb = (const float*)d_in[7];
    const float* Lg = (const float*)d_in[8];
    const float* Lb = (const float*)d_in[9];

    float* y    = (float*)d_out;
    float* attn = y + (size_t)L * DMODEL;               // output 1 (fp32), 268 MB

    // ws layout (bf16 elems), 40 MB:
    //   T0 [0,8MB): sums (128KB fp32) during attention, then Pw^T (8MB) for
    //               the proj GEMM (strictly after fused).
    //   qh [8,16), kh [16,24), vhT [24,32), O [32,40)
    //   ypre fp32 overlays qh+kh (dead after fused).
    // attn output region (268MB) is dead until fused writes it, so bf16
    // q,k,v (24MB) + Wq/Wk/Wv^T (24MB) are stashed there first.
    const size_t SEG = (size_t)4194304;
    unsigned short* T0  = (unsigned short*)d_ws;
    unsigned short* qh  = T0 + SEG;
    unsigned short* kh  = qh + SEG;
    unsigned short* vhT = kh + SEG;
    unsigned short* O   = vhT + SEG;
    float* ypre  = (float*)qh;
    float* sums  = (float*)d_ws;                        // [16][2048] fp32 = 128KB

    unsigned short* qkvb = (unsigned short*)attn;       // qb,kb,vb: 3 x SEG
    unsigned short* WT   = qkvb + 3 * SEG;              // WqT,WkT,WvT: 48 x 262144

    const float inv_temper = 0.022097086912079608f;     // 1/sqrt(2048)
    dim3 tb(32, 8);

    // Stage 0: merged cvt + weight transpose + sums zero (one launch).
    prep<<<dim3(18464), 256, 0, stream>>>(q, k, v, Wq, Wk, Wv, qkvb, WT, sums);

    // Stage 1: fused Q/K/V projections, 768 blocks, z -> XCD z&7 (SWZ=1).
    gemm_bt<3, 128, 64, 1><<<dim3(768), 256, 0, stream>>>(qkvb, WT, qh,
        2048, 2048, 2048, 0, 4194304LL, 262144LL, 262144LL, inv_temper);

    // Stage 2: stats — single-shot K=128 tiles, atomicAdd column exp-sums.
    stats_qk<<<dim3(4096), 256, 0, stream>>>(qh, kh, sums);

    // Stage 3: fused recompute-S + normalize + NT attn write + PV.
    // Counted-vmcnt pipeline (see kernel comment).
    fused_pv<<<dim3(512), 256, 0, stream>>>(qh, kh, vhT, sums, attn, O);

    // Stage 4: ypre = O @ proj_w.  512 blocks, B-panel -> XCD bx&7 (SWZ=3).
    transpose_f2b<<<dim3(64, 64, 1), tb, 0, stream>>>(Pw, T0, 2048, 2048);
    gemm_bt<2, 64, 64, 3><<<dim3(512), 256, 0, stream>>>(O, T0, (void*)ypre,
        2048, 2048, 2048, 2048, 0LL, 0LL, 0LL, 1.0f);

    // Stage 5: y = LayerNorm(ypre + proj_b + residual) * g + b
    ln_resid<<<dim3(2048), 256, 0, stream>>>(ypre, q, Pb, Lg, Lb, y);
}

// Round 13
// 577.510 us; speedup vs baseline: 1.0124x; 1.0124x over previous
//
#include <hip/hip_runtime.h>
#include <stdint.h>

#define L 2048
#define DMODEL 2048
#define NH 16

typedef __bf16 bf16x8 __attribute__((ext_vector_type(8)));
typedef float f32x4 __attribute__((ext_vector_type(4)));
typedef short s16x4 __attribute__((ext_vector_type(4)));

__device__ __forceinline__ unsigned short f2bf(float f) {
    union { float f; unsigned int i; } w; w.f = f;
    unsigned int u = w.i;
    unsigned int r = u + 0x7fffu + ((u >> 16) & 1u);
    return (unsigned short)(r >> 16);
}

// Async global->LDS, 16 bytes per lane.  LDS dest is wave-uniform base +
// lane*16 (m104); swizzled layouts are achieved by pre-swizzling the GLOBAL
// source address (rule 21: both-sides involution).
__device__ __forceinline__ void gload_lds16(const unsigned short* g, unsigned short* l) {
    __builtin_amdgcn_global_load_lds(
        (const __attribute__((address_space(1))) void*)g,
        (__attribute__((address_space(3))) void*)l, 16, 0, 0);
}

// ---------------------------------------------------------------------------
// Tiled bf16-MFMA GEMM, C = alpha * A (MxK) * B'(NxK)^T.  2-phase pipeline,
// double-buffered LDS, one __syncthreads per K-step.  LDS k-slot XOR-swizzle
// (rule 21).  CMODE 0/1/2 as before; CMODE 3 = fused QKV epilogue.
// SWZ 1: QKV 768 blocks (z -> XCD z&7); SWZ 3: proj 512 blocks (bx -> XCD).
// ---------------------------------------------------------------------------
template<int CMODE, int BM, int BK, int SWZ>
__global__ __launch_bounds__(256, 2)
void gemm_bt(const unsigned short* __restrict__ Ag,
             const unsigned short* __restrict__ B,
             void* __restrict__ C,
             int K, int lda, int ldb, int ldc,
             long long sA, long long sB, long long sC, float alpha)
{
    constexpr int KC8 = BK / 8;            // 16B slots per row
    constexpr int SWM = (KC8 >= 8) ? 7 : (KC8 - 1);
    constexpr int CA  = BM * BK / 2048;    // A chunks per thread
    constexpr int CB  = BK / 16;           // B chunks per thread (BN=128)
    constexpr int MFR = BM / 32;           // m-fragments per wave
    constexpr int KG  = BK / 32;           // MFMA K-groups per step

    __shared__ unsigned short As[2][BM * BK];
    __shared__ unsigned short Bs[2][128 * BK];

    int bx, by, bz;
    if constexpr (SWZ == 1) {            // QKV: 768 blocks
        const int xcd = blockIdx.x & 7, rest = blockIdx.x >> 3;  // rest<96
        bx = 0; by = rest & 15; bz = xcd + 8 * (rest >> 4);
    } else if constexpr (SWZ == 3) {     // proj: 512 blocks
        const int xcd = blockIdx.x & 7, rest = blockIdx.x >> 3;  // rest<64
        bx = xcd + 8 * (rest >> 5); by = rest & 31; bz = 0;
    } else {
        bx = blockIdx.x; by = blockIdx.y; bz = blockIdx.z;
    }

    const int tid  = threadIdx.x;
    const int wave = tid >> 6;
    const int lane = tid & 63;
    const int quad = lane >> 4;
    const int l16  = lane & 15;

    const int tileN = bx * 128;
    const int tileM = by * BM;

    const long long zA = (CMODE == 3) ? (long long)(bz >> 4) : (long long)bz;
    const unsigned short* A16 = Ag + zA * sA;
    B += (long long)bz * sB;

    const int wm = (wave >> 1) * (BM / 2);
    const int wn = (wave & 1) * 64;

    auto stageB = [&](int kk, int buf) {
        #pragma unroll
        for (int j = 0; j < CB; ++j) {
            const int ch = tid + j * 256;
            const int rb = ch / KC8, sl = (ch % KC8) ^ (rb & SWM);
            gload_lds16(B + (long long)(tileN + rb) * ldb + (kk + sl * 8), &Bs[buf][ch * 8]);
        }
    };
    auto stageA = [&](int kk, int buf) {
        #pragma unroll
        for (int j = 0; j < CA; ++j) {
            const int ch = tid + j * 256;
            const int ra = ch / KC8, sl = (ch % KC8) ^ (ra & SWM);
            gload_lds16(A16 + (long long)(tileM + ra) * lda + (kk + sl * 8), &As[buf][ch * 8]);
        }
    };

    f32x4 acc[MFR][4] = {};
    const int nt = K / BK;

    stageA(0, 0);
    stageB(0, 0);
    __syncthreads();

    int cur = 0;
    for (int t = 0; t < nt; ++t) {
        const int nxt = cur ^ 1;
        const int k0n = (t + 1) * BK;
        if (t + 1 < nt) { stageA(k0n, nxt); stageB(k0n, nxt); }

        bf16x8 af[MFR][KG], bfr[4][KG];
        #pragma unroll
        for (int i = 0; i < MFR; ++i) {
            const int rr = wm + i * 16 + l16;
            #pragma unroll
            for (int g = 0; g < KG; ++g)
                af[i][g] = *(const bf16x8*)(&As[cur][rr * BK + ((g * 32 + quad * 8) ^ ((rr & SWM) << 3))]);
        }
        #pragma unroll
        for (int j = 0; j < 4; ++j) {
            const int rr = wn + j * 16 + l16;
            #pragma unroll
            for (int g = 0; g < KG; ++g)
                bfr[j][g] = *(const bf16x8*)(&Bs[cur][rr * BK + ((g * 32 + quad * 8) ^ ((rr & SWM) << 3))]);
        }
        #pragma unroll
        for (int g = 0; g < KG; ++g)
            #pragma unroll
            for (int i = 0; i < MFR; ++i)
                #pragma unroll
                for (int j = 0; j < 4; ++j)
                    acc[i][j] = __builtin_amdgcn_mfma_f32_16x16x32_bf16(af[i][g], bfr[j][g], acc[i][j], 0, 0, 0);

        __syncthreads();
        cur = nxt;
    }

    // Epilogue.  D layout: col = lane&15, row = quad*4+reg  [m89-verified]
    const long long cb = (long long)bz * sC;
    const float aEff = (CMODE == 3) ? (bz < 16 ? alpha : 1.0f) : alpha;
    #pragma unroll
    for (int i = 0; i < MFR; ++i) {
        const int r0 = tileM + wm + i * 16 + quad * 4;
        #pragma unroll
        for (int j = 0; j < 4; ++j) {
            const int c = tileN + wn + j * 16 + l16;
            f32x4 d = acc[i][j];
            if (CMODE == 0) {
                unsigned short* Cp = (unsigned short*)C + cb;
                #pragma unroll
                for (int r = 0; r < 4; ++r)
                    Cp[(long long)(r0 + r) * ldc + c] = f2bf(d[r] * aEff);
            } else if (CMODE == 1) {
                unsigned short* Cp = (unsigned short*)C + cb + (long long)c * ldc + r0;
                s16x4 pk;
                #pragma unroll
                for (int r = 0; r < 4; ++r) pk[r] = (short)f2bf(d[r] * aEff);
                *(s16x4*)Cp = pk;
            } else if (CMODE == 2) {
                float* Cp = (float*)C + cb;
                #pragma unroll
                for (int r = 0; r < 4; ++r)
                    Cp[(long long)(r0 + r) * ldc + c] = d[r] * aEff;
            } else { // CMODE 3: fused QKV
                if (bz < 32) {                  // qh/kh, bf16 row-major, ldc=128
                    unsigned short* Cp = (unsigned short*)C + cb;
                    #pragma unroll
                    for (int r = 0; r < 4; ++r)
                        Cp[(long long)(r0 + r) * 128 + c] = f2bf(d[r] * aEff);
                } else {                         // vhT, bf16 transposed, ldc=2048
                    unsigned short* Cp = (unsigned short*)C + cb + (long long)c * 2048 + r0;
                    s16x4 pk;
                    #pragma unroll
                    for (int r = 0; r < 4; ++r) pk[r] = (short)f2bf(d[r]);
                    *(s16x4*)Cp = pk;
                }
            }
        }
    }
}

// ---------------------------------------------------------------------------
// stats: S = qh[h] @ kh[h]^T per 128x128 tile, K=128 single-shot (one stage,
// one barrier).  No C write; atomicAdd per-column exp-sums (no-max softmax,
// fp32-safe).  Grid 4096 linear, head -> XCD h&7.  LDS 64KB, 2 blocks/CU.
// ---------------------------------------------------------------------------
__global__ __launch_bounds__(256, 2)
void stats_qk(const unsigned short* __restrict__ qh,
              const unsigned short* __restrict__ kh,
              float* __restrict__ sums)
{
    __shared__ unsigned short As[128 * 128];
    __shared__ unsigned short Bs[128 * 128];

    const int xcd = blockIdx.x & 7, rest = blockIdx.x >> 3;  // rest<512
    const int inner = rest & 255;
    const int bx = inner & 15, by = inner >> 4;
    const int bz = xcd + 8 * (rest >> 8);

    const int tid = threadIdx.x;
    const int wave = tid >> 6, lane = tid & 63, quad = lane >> 4, l16 = lane & 15;
    const int tileN = bx * 128, tileM = by * 128;
    const int wm = (wave >> 1) * 64, wn = (wave & 1) * 64;

    const unsigned short* A16 = qh + (long long)bz * 262144;
    const unsigned short* B16 = kh + (long long)bz * 262144;

    #pragma unroll
    for (int j = 0; j < 8; ++j) {          // 2048 chunks per tile, 8/thread
        const int ch = tid + j * 256;
        const int rr = ch >> 4, sl = (ch & 15) ^ (rr & 7);
        gload_lds16(A16 + (long long)(tileM + rr) * 128 + sl * 8, &As[ch * 8]);
        gload_lds16(B16 + (long long)(tileN + rr) * 128 + sl * 8, &Bs[ch * 8]);
    }
    __syncthreads();

    f32x4 acc[4][4] = {};
    #pragma unroll
    for (int g = 0; g < 4; ++g) {
        bf16x8 af[4], bfr[4];
        #pragma unroll
        for (int i = 0; i < 4; ++i) {
            const int rr = wm + i * 16 + l16;
            af[i] = *(const bf16x8*)(&As[rr * 128 + ((g * 32 + quad * 8) ^ ((rr & 7) << 3))]);
        }
        #pragma unroll
        for (int j = 0; j < 4; ++j) {
            const int rr = wn + j * 16 + l16;
            bfr[j] = *(const bf16x8*)(&Bs[rr * 128 + ((g * 32 + quad * 8) ^ ((rr & 7) << 3))]);
        }
        #pragma unroll
        for (int i = 0; i < 4; ++i)
            #pragma unroll
            for (int j = 0; j < 4; ++j)
                acc[i][j] = __builtin_amdgcn_mfma_f32_16x16x32_bf16(af[i], bfr[j], acc[i][j], 0, 0, 0);
    }

    // column exp-sums: butterfly over quads (rows), one atomic per col per wave
    float* sc = sums + (long long)bz * 2048;
    #pragma unroll
    for (int j = 0; j < 4; ++j) {
        float ej = 0.f;
        #pragma unroll
        for (int i = 0; i < 4; ++i)
            #pragma unroll
            for (int r = 0; r < 4; ++r) ej += __expf(acc[i][j][r]);
        ej += __shfl_xor(ej, 16, 64);
        ej += __shfl_xor(ej, 32, 64);
        if (quad == 0)
            atomicAdd(&sc[tileN + wn + j * 16 + l16], ej);
    }
}

// ---------------------------------------------------------------------------
// Fused scores+softmax+PV.  Grid 512 linear = 8 XCD x (32 qt x 2 hi).
// Block 256 (4 waves); per block q rows [qt*64,+64), head h.
// qh fragments loop-invariant in 64 VGPR (loaded once from global).
// Loop 64 key-tiles of 32: stage(t+1) -> S^T(t)=kh@bq -> p=exp(s)*rcp(sum)
// -> NT attn write + p16 pack -> barrier -> PV(t).
// kh dbuf, vh TRIPLE buf (read post-barrier), p16 dbuf: race-free, 1 barrier
// per tile.  LDS 48KB.
// [R12 counted-vmcnt variant REVERTED: NT stores + sums loads share the
//  vmcnt queue, so vmcnt(4) waited on store retirement -> -16us regression.]
// ---------------------------------------------------------------------------
__global__ __launch_bounds__(256, 2)
void fused_pv(const unsigned short* __restrict__ qh,
              const unsigned short* __restrict__ kh,
              const unsigned short* __restrict__ vhT,
              const float* __restrict__ sums,
              float* __restrict__ attn, unsigned short* __restrict__ O)
{
    __shared__ unsigned short kh_s[2][32 * 128];
    __shared__ unsigned short vh_s[3][128 * 32];
    __shared__ unsigned short p16[2][64 * 32];

    const int tid = threadIdx.x;
    const int wave = tid >> 6, lane = tid & 63, quad = lane >> 4, l16 = lane & 15;
    const int slot = blockIdx.x >> 3;
    const int qt = slot & 31;
    const int h  = (blockIdx.x & 7) + 8 * (slot >> 5);
    const int wA = wave >> 1, wB = wave & 1;   // S:  wA=key-half(16), wB=q-half(32)
                                               // PV: wA=q-half(32),   wB=vd-half(64)
    const unsigned short* qg = qh + (long long)h * 262144 + (long long)qt * 64 * 128;
    const unsigned short* kg = kh + (long long)h * 262144;
    const unsigned short* vg = vhT + (long long)h * 262144;
    const float* smp = sums + h * 2048;
    float* ap = attn + (long long)h * L * L + (long long)qt * 64 * 2048;

    auto stage_kv = [&](int kt, int kb_, int vb_) {
        #pragma unroll
        for (int jj = 0; jj < 2; ++jj) {       // kh tile: 32 rows x 128 dk = 512 chunks
            const int c = tid + jj * 256;
            const int rl = c >> 4, sl = (c & 15) ^ (rl & 7);
            gload_lds16(kg + (long long)(kt * 32 + rl) * 128 + sl * 8, &kh_s[kb_][c * 8]);
        }
        #pragma unroll
        for (int jj = 0; jj < 2; ++jj) {       // vh tile: 128 vd x 32 keys = 512 chunks
            const int c = tid + jj * 256;
            const int vd = c >> 2, sl = (c & 3) ^ (vd & 3);
            gload_lds16(vg + (long long)vd * 2048 + kt * 32 + sl * 8, &vh_s[vb_][c * 8]);
        }
    };

    // prologue: qh fragments straight into registers (loop-invariant).
    // bq[j][g] covers q = wB*32+j*16+l16, dk = g*32+quad*8..+8.
    bf16x8 bq[2][4];
    #pragma unroll
    for (int j = 0; j < 2; ++j) {
        const int q = wB * 32 + j * 16 + l16;
        #pragma unroll
        for (int g = 0; g < 4; ++g)
            bq[j][g] = *(const bf16x8*)(qg + (long long)q * 128 + g * 32 + quad * 8);
    }
    stage_kv(0, 0, 0);
    __syncthreads();

    f32x4 acc_o[2][4] = {};
    const int krow = wA * 16 + l16;            // S A-operand row (key, local)

    for (int t = 0; t < 64; ++t) {
        const int cb = t & 1;
        const int vb3 = t % 3;
        if (t < 63) stage_kv(t + 1, cb ^ 1, (t + 1) % 3);

        // prefetch this tile's key exp-sums (L2-hot 128KB table)
        const int kb = t * 32 + wA * 16 + quad * 4;
        const f32x4 sg4 = *(const f32x4*)(smp + kb);

        // S^T(t): A=kh (M=key 32), B=bq regs.  8 MFMA/wave.
        bf16x8 af[4];
        #pragma unroll
        for (int g = 0; g < 4; ++g)
            af[g] = *(const bf16x8*)(&kh_s[cb][krow * 128 + ((g * 32 + quad * 8) ^ ((krow & 7) << 3))]);
        f32x4 acc_s[2];
        __builtin_amdgcn_s_setprio(1);
        #pragma unroll
        for (int j = 0; j < 2; ++j) {
            f32x4 s = {};
            #pragma unroll
            for (int g = 0; g < 4; ++g)
                s = __builtin_amdgcn_mfma_f32_16x16x32_bf16(af[g], bq[j][g], s, 0, 0, 0);
            acc_s[j] = s;
        }
        __builtin_amdgcn_s_setprio(0);

        // normalize (p = exp(s) * 1/sum) + NT attn write + p16 pack.
        // D: row(key)=quad*4+r, col(q)=l16.
        f32x4 il4;
        #pragma unroll
        for (int r = 0; r < 4; ++r) il4[r] = __builtin_amdgcn_rcpf(sg4[r]);
        #pragma unroll
        for (int j = 0; j < 2; ++j) {
            const int q = wB * 32 + j * 16 + l16;
            f32x4 p;
            #pragma unroll
            for (int r = 0; r < 4; ++r)
                p[r] = __expf(acc_s[j][r]) * il4[r];
            __builtin_nontemporal_store(p, (f32x4*)(ap + (long long)q * 2048 + kb));
            s16x4 pk;
            #pragma unroll
            for (int r = 0; r < 4; ++r) pk[r] = (short)f2bf(p[r]);
            *(s16x4*)(&p16[cb][q * 32 + ((wA * 16 + quad * 4) ^ ((q & 3) << 3))]) = pk;
        }

        __syncthreads();   // p16(t) visible; stage(t+1) drained; S reads done

        // PV(t): P (64q x 32k) @ vh^T.  8 MFMA/wave.
        bf16x8 pa[2], vb[4];
        #pragma unroll
        for (int i = 0; i < 2; ++i) {
            const int qq = wA * 32 + i * 16 + l16;
            pa[i] = *(const bf16x8*)(&p16[cb][qq * 32 + ((quad * 8) ^ ((qq & 3) << 3))]);
        }
        #pragma unroll
        for (int j = 0; j < 4; ++j) {
            const int vd = wB * 64 + j * 16 + l16;
            vb[j] = *(const bf16x8*)(&vh_s[vb3][vd * 32 + ((quad * 8) ^ ((vd & 3) << 3))]);
        }
        __builtin_amdgcn_s_setprio(1);
        #pragma unroll
        for (int i = 0; i < 2; ++i)
            #pragma unroll
            for (int j = 0; j < 4; ++j)
                acc_o[i][j] = __builtin_amdgcn_mfma_f32_16x16x32_bf16(pa[i], vb[j], acc_o[i][j], 0, 0, 0);
        __builtin_amdgcn_s_setprio(0);
    }

    // O epilogue: O[q][h*128+vd] bf16.  D: row(q)=quad*4+r, col(vd)=l16.
    #pragma unroll
    for (int i = 0; i < 2; ++i) {
        const int q = qt * 64 + wA * 32 + i * 16 + quad * 4;
        #pragma unroll
        for (int j = 0; j < 4; ++j) {
            const int vd = h * 128 + wB * 64 + j * 16 + l16;
            #pragma unroll
            for (int r = 0; r < 4; ++r)
                O[(long long)(q + r) * 2048 + vd] = f2bf(acc_o[i][j][r]);
        }
    }
}

// ---------------------------------------------------------------------------
// prep: merged stage-0 (3 launches -> 1).  Flat grid 18464 x 256:
//   [0, 6144):       q,k,v fp32 -> bf16  (z = bid/2048, 8 elems/thread)
//   [6144, 18432):   Wq/Wk/Wv transpose+cvt (48 heads x 4x64 32-tiles)
//   [18432, 18464):  zero the exp-sums table (32K floats)
// ---------------------------------------------------------------------------
__global__ __launch_bounds__(256)
void prep(const float* __restrict__ q, const float* __restrict__ k,
          const float* __restrict__ v,
          const float* __restrict__ Wq, const float* __restrict__ Wk,
          const float* __restrict__ Wv,
          unsigned short* __restrict__ qkvb, unsigned short* __restrict__ WT,
          float* __restrict__ sums)
{
    __shared__ float t[32][33];
    const int bid = blockIdx.x;
    const int tid = threadIdx.x;

    if (bid < 6144) {                      // ---- cvt q,k,v ----
        const int z = bid >> 11, xb = bid & 2047;
        const float* in = z == 0 ? q : z == 1 ? k : v;
        const long long i = ((long long)xb * 256 + tid) * 8;
        const float4 f0 = *(const float4*)(in + i);
        const float4 f1 = *(const float4*)(in + i + 4);
        union { int4 v4; unsigned short u[8]; } tt;
        tt.u[0] = f2bf(f0.x); tt.u[1] = f2bf(f0.y); tt.u[2] = f2bf(f0.z); tt.u[3] = f2bf(f0.w);
        tt.u[4] = f2bf(f1.x); tt.u[5] = f2bf(f1.y); tt.u[6] = f2bf(f1.z); tt.u[7] = f2bf(f1.w);
        *(int4*)(qkvb + (long long)z * 4194304 + i) = tt.v4;
    } else if (bid < 18432) {              // ---- weight transpose ----
        const int r = bid - 6144;
        const int z = r >> 8, rr = r & 255;
        const int bx = rr & 3, by = rr >> 2;
        const int widx = z >> 4, hh = z & 15;
        const float* in = (widx == 0 ? Wq : widx == 1 ? Wk : Wv) + (long long)hh * 2048 * 128;
        unsigned short* o = WT + (long long)z * 262144;
        const int c0 = bx * 32, r0 = by * 32;
        const int tx = tid & 31, ty0 = tid >> 5;
        #pragma unroll
        for (int jj = 0; jj < 4; ++jj) {
            const int j = ty0 + jj * 8;
            t[j][tx] = in[(long long)(r0 + j) * 128 + (c0 + tx)];
        }
        __syncthreads();
        #pragma unroll
        for (int jj = 0; jj < 4; ++jj) {
            const int j = ty0 + jj * 8;
            o[(long long)(c0 + j) * 2048 + (r0 + tx)] = f2bf(t[tx][j]);
        }
    } else {                               // ---- zero sums ----
        const int bt = bid - 18432;
        float4 zz = {0.f, 0.f, 0.f, 0.f};
        ((float4*)sums)[bt * 256 + tid] = zz;
    }
}

// ---------------------------------------------------------------------------
// 32x32 tile transpose, fp32 in -> bf16 out. Block (32,8).  (Pw only.)
// ---------------------------------------------------------------------------
__global__ __launch_bounds__(256)
void transpose_f2b(const float* __restrict__ in, unsigned short* __restrict__ out,
                   int rows, int cols)
{
    __shared__ float t[32][33];
    const long long base = (long long)blockIdx.z * rows * cols;
    const int c0 = blockIdx.x * 32, r0 = blockIdx.y * 32;
    const int tx = threadIdx.x, ty0 = threadIdx.y;
    #pragma unroll
    for (int jj = 0; jj < 4; ++jj) {
        const int j = ty0 + jj * 8;
        t[j][tx] = in[base + (long long)(r0 + j) * cols + (c0 + tx)];
    }
    __syncthreads();
    #pragma unroll
    for (int jj = 0; jj < 4; ++jj) {
        const int j = ty0 + jj * 8;
        out[base + (long long)(c0 + j) * rows + (r0 + tx)] = f2bf(t[tx][j]);
    }
}

// ---------------------------------------------------------------------------
// Residual + bias + LayerNorm (all fp32), one block (256 thr) per row of 2048.
// float4 loads/stores (G13: 16B/lane; scalar 4B was ~half-BW on 48MB traffic).
// ---------------------------------------------------------------------------
__global__ __launch_bounds__(256)
void ln_resid(const float* __restrict__ ypre, const float* __restrict__ resid,
              const float* __restrict__ pb, const float* __restrict__ g,
              const float* __restrict__ bta, float* __restrict__ y)
{
    __shared__ float as_[4], as2_[4];
    const int l = blockIdx.x;
    const int tid = threadIdx.x;
    const float4* yp4 = (const float4*)(ypre + (long long)l * DMODEL);
    const float4* rd4 = (const float4*)(resid + (long long)l * DMODEL);
    const float4* pb4 = (const float4*)pb;

    float4 v[2]; float s = 0.f, s2 = 0.f;
    #pragma unroll
    for (int i = 0; i < 2; ++i) {
        const int d = tid + i * 256;
        const float4 a = yp4[d], b = rd4[d], c = pb4[d];
        float4 t;
        t.x = a.x + c.x + b.x;  t.y = a.y + c.y + b.y;
        t.z = a.z + c.z + b.z;  t.w = a.w + c.w + b.w;
        v[i] = t;
        s  += t.x + t.y + t.z + t.w;
        s2 += t.x * t.x + t.y * t.y + t.z * t.z + t.w * t.w;
    }
    #pragma unroll
    for (int off = 32; off > 0; off >>= 1) {
        s  += __shfl_down(s, off, 64);
        s2 += __shfl_down(s2, off, 64);
    }
    const int wave = tid >> 6, lane = tid & 63;
    if (lane == 0) { as_[wave] = s; as2_[wave] = s2; }
    __syncthreads();
    const float S  = as_[0] + as_[1] + as_[2] + as_[3];
    const float S2 = as2_[0] + as2_[1] + as2_[2] + as2_[3];
    const float mu  = S * (1.0f / DMODEL);
    const float var = S2 * (1.0f / DMODEL) - mu * mu;
    const float rs  = rsqrtf(var + 1e-5f);
    const float4* g4 = (const float4*)g;
    const float4* b4 = (const float4*)bta;
    float4* y4 = (float4*)(y + (long long)l * DMODEL);
    #pragma unroll
    for (int i = 0; i < 2; ++i) {
        const int d = tid + i * 256;
        const float4 gg = g4[d], bb = b4[d], t = v[i];
        float4 o;
        o.x = (t.x - mu) * rs * gg.x + bb.x;  o.y = (t.y - mu) * rs * gg.y + bb.y;
        o.z = (t.z - mu) * rs * gg.z + bb.z;  o.w = (t.w - mu) * rs * gg.w + bb.w;
        y4[d] = o;
    }
}

// ---------------------------------------------------------------------------
extern "C" void kernel_launch(void* const* d_in, const int* in_sizes, int n_in,
                              void* d_out, int out_size, void* d_ws, size_t ws_size,
                              hipStream_t stream)
{
    const float* q  = (const float*)d_in[0];
    const float* k  = (const float*)d_in[1];
    const float* v  = (const float*)d_in[2];
    const float* Wq = (const float*)d_in[3];
    const float* Wk = (const float*)d_in[4];
    const float* Wv = (const float*)d_in[5];
    const float* Pw = (const float*)d_in[6];
    const float* Pb = (const float*)d_in[7];
    const float* Lg = (const float*)d_in[8];
    const float* Lb = (const float*)d_in[9];

    float* y    = (float*)d_out;
    float* attn = y + (size_t)L * DMODEL;               // output 1 (fp32), 268 MB

    // ws layout (bf16 elems), 40 MB:
    //   T0 [0,8MB): sums (128KB fp32) during attention, then Pw^T (8MB) for
    //               the proj GEMM (strictly after fused).
    //   qh [8,16), kh [16,24), vhT [24,32), O [32,40)
    //   ypre fp32 overlays qh+kh (dead after fused).
    // attn output region (268MB) is dead until fused writes it, so bf16
    // q,k,v (24MB) + Wq/Wk/Wv^T (24MB) are stashed there first.
    const size_t SEG = (size_t)4194304;
    unsigned short* T0  = (unsigned short*)d_ws;
    unsigned short* qh  = T0 + SEG;
    unsigned short* kh  = qh + SEG;
    unsigned short* vhT = kh + SEG;
    unsigned short* O   = vhT + SEG;
    float* ypre  = (float*)qh;
    float* sums  = (float*)d_ws;                        // [16][2048] fp32 = 128KB

    unsigned short* qkvb = (unsigned short*)attn;       // qb,kb,vb: 3 x SEG
    unsigned short* WT   = qkvb + 3 * SEG;              // WqT,WkT,WvT: 48 x 262144

    const float inv_temper = 0.022097086912079608f;     // 1/sqrt(2048)
    dim3 tb(32, 8);

    // Stage 0: merged cvt + weight transpose + sums zero (one launch).
    prep<<<dim3(18464), 256, 0, stream>>>(q, k, v, Wq, Wk, Wv, qkvb, WT, sums);

    // Stage 1: fused Q/K/V projections, 768 blocks, z -> XCD z&7 (SWZ=1).
    gemm_bt<3, 128, 64, 1><<<dim3(768), 256, 0, stream>>>(qkvb, WT, qh,
        2048, 2048, 2048, 0, 4194304LL, 262144LL, 262144LL, inv_temper);

    // Stage 2: stats — single-shot K=128 tiles, atomicAdd column exp-sums.
    stats_qk<<<dim3(4096), 256, 0, stream>>>(qh, kh, sums);

    // Stage 3: fused recompute-S + normalize + NT attn write + PV.
    fused_pv<<<dim3(512), 256, 0, stream>>>(qh, kh, vhT, sums, attn, O);

    // Stage 4: ypre = O @ proj_w.  512 blocks, B-panel -> XCD bx&7 (SWZ=3).
    transpose_f2b<<<dim3(64, 64, 1), tb, 0, stream>>>(Pw, T0, 2048, 2048);
    gemm_bt<2, 64, 64, 3><<<dim3(512), 256, 0, stream>>>(O, T0, (void*)ypre,
        2048, 2048, 2048, 2048, 0LL, 0LL, 0LL, 1.0f);

    // Stage 5: y = LayerNorm(ypre + proj_b + residual) * g + b
    ln_resid<<<dim3(2048), 256, 0, stream>>>(ypre, q, Pb, Lg, Lb, y);
}

// Round 14
// 556.309 us; speedup vs baseline: 1.0509x; 1.0381x over previous
//
#include <hip/hip_runtime.h>
#include <stdint.h>

#define L 2048
#define DMODEL 2048
#define NH 16

typedef __bf16 bf16x8 __attribute__((ext_vector_type(8)));
typedef float f32x4 __attribute__((ext_vector_type(4)));
typedef short s16x4 __attribute__((ext_vector_type(4)));

__device__ __forceinline__ unsigned short f2bf(float f) {
    union { float f; unsigned int i; } w; w.f = f;
    unsigned int u = w.i;
    unsigned int r = u + 0x7fffu + ((u >> 16) & 1u);
    return (unsigned short)(r >> 16);
}

// Async global->LDS, 16 bytes per lane.  LDS dest is wave-uniform base +
// lane*16 (m104); swizzled layouts are achieved by pre-swizzling the GLOBAL
// source address (rule 21: both-sides involution).
__device__ __forceinline__ void gload_lds16(const unsigned short* g, unsigned short* l) {
    __builtin_amdgcn_global_load_lds(
        (const __attribute__((address_space(1))) void*)g,
        (__attribute__((address_space(3))) void*)l, 16, 0, 0);
}

// ---------------------------------------------------------------------------
// Tiled bf16-MFMA GEMM, C = alpha * A (MxK) * B'(NxK)^T.  2-phase pipeline,
// double-buffered LDS, one __syncthreads per K-step.  LDS k-slot XOR-swizzle
// (rule 21).  CMODE 0/1/2 as before; CMODE 3 = fused QKV epilogue.
// SWZ 1: QKV 768 blocks (z -> XCD z&7); SWZ 3: proj 512 blocks (bx -> XCD).
// MW = __launch_bounds__ min-waves/EU.  BK=32 keeps LDS at 32KB -> 3
// blocks/CU with MW=3 (m132: 64KB LDS costs the 3rd block, 874->508 TF).
// ---------------------------------------------------------------------------
template<int CMODE, int BM, int BK, int SWZ, int MW>
__global__ __launch_bounds__(256, MW)
void gemm_bt(const unsigned short* __restrict__ Ag,
             const unsigned short* __restrict__ B,
             void* __restrict__ C,
             int K, int lda, int ldb, int ldc,
             long long sA, long long sB, long long sC, float alpha)
{
    constexpr int KC8 = BK / 8;            // 16B slots per row
    constexpr int SWM = (KC8 >= 8) ? 7 : (KC8 - 1);
    constexpr int CA  = BM * BK / 2048;    // A chunks per thread
    constexpr int CB  = BK / 16;           // B chunks per thread (BN=128)
    constexpr int MFR = BM / 32;           // m-fragments per wave
    constexpr int KG  = BK / 32;           // MFMA K-groups per step

    __shared__ unsigned short As[2][BM * BK];
    __shared__ unsigned short Bs[2][128 * BK];

    int bx, by, bz;
    if constexpr (SWZ == 1) {            // QKV: 768 blocks
        const int xcd = blockIdx.x & 7, rest = blockIdx.x >> 3;  // rest<96
        bx = 0; by = rest & 15; bz = xcd + 8 * (rest >> 4);
    } else if constexpr (SWZ == 3) {     // proj: 512 blocks
        const int xcd = blockIdx.x & 7, rest = blockIdx.x >> 3;  // rest<64
        bx = xcd + 8 * (rest >> 5); by = rest & 31; bz = 0;
    } else {
        bx = blockIdx.x; by = blockIdx.y; bz = blockIdx.z;
    }

    const int tid  = threadIdx.x;
    const int wave = tid >> 6;
    const int lane = tid & 63;
    const int quad = lane >> 4;
    const int l16  = lane & 15;

    const int tileN = bx * 128;
    const int tileM = by * BM;

    const long long zA = (CMODE == 3) ? (long long)(bz >> 4) : (long long)bz;
    const unsigned short* A16 = Ag + zA * sA;
    B += (long long)bz * sB;

    const int wm = (wave >> 1) * (BM / 2);
    const int wn = (wave & 1) * 64;

    auto stageB = [&](int kk, int buf) {
        #pragma unroll
        for (int j = 0; j < CB; ++j) {
            const int ch = tid + j * 256;
            const int rb = ch / KC8, sl = (ch % KC8) ^ (rb & SWM);
            gload_lds16(B + (long long)(tileN + rb) * ldb + (kk + sl * 8), &Bs[buf][ch * 8]);
        }
    };
    auto stageA = [&](int kk, int buf) {
        #pragma unroll
        for (int j = 0; j < CA; ++j) {
            const int ch = tid + j * 256;
            const int ra = ch / KC8, sl = (ch % KC8) ^ (ra & SWM);
            gload_lds16(A16 + (long long)(tileM + ra) * lda + (kk + sl * 8), &As[buf][ch * 8]);
        }
    };

    f32x4 acc[MFR][4] = {};
    const int nt = K / BK;

    stageA(0, 0);
    stageB(0, 0);
    __syncthreads();

    int cur = 0;
    for (int t = 0; t < nt; ++t) {
        const int nxt = cur ^ 1;
        const int k0n = (t + 1) * BK;
        if (t + 1 < nt) { stageA(k0n, nxt); stageB(k0n, nxt); }

        bf16x8 af[MFR][KG], bfr[4][KG];
        #pragma unroll
        for (int i = 0; i < MFR; ++i) {
            const int rr = wm + i * 16 + l16;
            #pragma unroll
            for (int g = 0; g < KG; ++g)
                af[i][g] = *(const bf16x8*)(&As[cur][rr * BK + ((g * 32 + quad * 8) ^ ((rr & SWM) << 3))]);
        }
        #pragma unroll
        for (int j = 0; j < 4; ++j) {
            const int rr = wn + j * 16 + l16;
            #pragma unroll
            for (int g = 0; g < KG; ++g)
                bfr[j][g] = *(const bf16x8*)(&Bs[cur][rr * BK + ((g * 32 + quad * 8) ^ ((rr & SWM) << 3))]);
        }
        #pragma unroll
        for (int g = 0; g < KG; ++g)
            #pragma unroll
            for (int i = 0; i < MFR; ++i)
                #pragma unroll
                for (int j = 0; j < 4; ++j)
                    acc[i][j] = __builtin_amdgcn_mfma_f32_16x16x32_bf16(af[i][g], bfr[j][g], acc[i][j], 0, 0, 0);

        __syncthreads();
        cur = nxt;
    }

    // Epilogue.  D layout: col = lane&15, row = quad*4+reg  [m89-verified]
    const long long cb = (long long)bz * sC;
    const float aEff = (CMODE == 3) ? (bz < 16 ? alpha : 1.0f) : alpha;
    #pragma unroll
    for (int i = 0; i < MFR; ++i) {
        const int r0 = tileM + wm + i * 16 + quad * 4;
        #pragma unroll
        for (int j = 0; j < 4; ++j) {
            const int c = tileN + wn + j * 16 + l16;
            f32x4 d = acc[i][j];
            if (CMODE == 0) {
                unsigned short* Cp = (unsigned short*)C + cb;
                #pragma unroll
                for (int r = 0; r < 4; ++r)
                    Cp[(long long)(r0 + r) * ldc + c] = f2bf(d[r] * aEff);
            } else if (CMODE == 1) {
                unsigned short* Cp = (unsigned short*)C + cb + (long long)c * ldc + r0;
                s16x4 pk;
                #pragma unroll
                for (int r = 0; r < 4; ++r) pk[r] = (short)f2bf(d[r] * aEff);
                *(s16x4*)Cp = pk;
            } else if (CMODE == 2) {
                float* Cp = (float*)C + cb;
                #pragma unroll
                for (int r = 0; r < 4; ++r)
                    Cp[(long long)(r0 + r) * ldc + c] = d[r] * aEff;
            } else { // CMODE 3: fused QKV
                if (bz < 32) {                  // qh/kh, bf16 row-major, ldc=128
                    unsigned short* Cp = (unsigned short*)C + cb;
                    #pragma unroll
                    for (int r = 0; r < 4; ++r)
                        Cp[(long long)(r0 + r) * 128 + c] = f2bf(d[r] * aEff);
                } else {                         // vhT, bf16 transposed, ldc=2048
                    unsigned short* Cp = (unsigned short*)C + cb + (long long)c * 2048 + r0;
                    s16x4 pk;
                    #pragma unroll
                    for (int r = 0; r < 4; ++r) pk[r] = (short)f2bf(d[r]);
                    *(s16x4*)Cp = pk;
                }
            }
        }
    }
}

// ---------------------------------------------------------------------------
// stats: S = qh[h] @ kh[h]^T per 128x128 tile, K=128 single-shot (one stage,
// one barrier).  No C write; atomicAdd per-column exp-sums (no-max softmax,
// fp32-safe).  Grid 4096 linear, head -> XCD h&7.  LDS 64KB, 2 blocks/CU.
// ---------------------------------------------------------------------------
__global__ __launch_bounds__(256, 2)
void stats_qk(const unsigned short* __restrict__ qh,
              const unsigned short* __restrict__ kh,
              float* __restrict__ sums)
{
    __shared__ unsigned short As[128 * 128];
    __shared__ unsigned short Bs[128 * 128];

    const int xcd = blockIdx.x & 7, rest = blockIdx.x >> 3;  // rest<512
    const int inner = rest & 255;
    const int bx = inner & 15, by = inner >> 4;
    const int bz = xcd + 8 * (rest >> 8);

    const int tid = threadIdx.x;
    const int wave = tid >> 6, lane = tid & 63, quad = lane >> 4, l16 = lane & 15;
    const int tileN = bx * 128, tileM = by * 128;
    const int wm = (wave >> 1) * 64, wn = (wave & 1) * 64;

    const unsigned short* A16 = qh + (long long)bz * 262144;
    const unsigned short* B16 = kh + (long long)bz * 262144;

    #pragma unroll
    for (int j = 0; j < 8; ++j) {          // 2048 chunks per tile, 8/thread
        const int ch = tid + j * 256;
        const int rr = ch >> 4, sl = (ch & 15) ^ (rr & 7);
        gload_lds16(A16 + (long long)(tileM + rr) * 128 + sl * 8, &As[ch * 8]);
        gload_lds16(B16 + (long long)(tileN + rr) * 128 + sl * 8, &Bs[ch * 8]);
    }
    __syncthreads();

    f32x4 acc[4][4] = {};
    #pragma unroll
    for (int g = 0; g < 4; ++g) {
        bf16x8 af[4], bfr[4];
        #pragma unroll
        for (int i = 0; i < 4; ++i) {
            const int rr = wm + i * 16 + l16;
            af[i] = *(const bf16x8*)(&As[rr * 128 + ((g * 32 + quad * 8) ^ ((rr & 7) << 3))]);
        }
        #pragma unroll
        for (int j = 0; j < 4; ++j) {
            const int rr = wn + j * 16 + l16;
            bfr[j] = *(const bf16x8*)(&Bs[rr * 128 + ((g * 32 + quad * 8) ^ ((rr & 7) << 3))]);
        }
        #pragma unroll
        for (int i = 0; i < 4; ++i)
            #pragma unroll
            for (int j = 0; j < 4; ++j)
                acc[i][j] = __builtin_amdgcn_mfma_f32_16x16x32_bf16(af[i], bfr[j], acc[i][j], 0, 0, 0);
    }

    // column exp-sums: butterfly over quads (rows), one atomic per col per wave
    float* sc = sums + (long long)bz * 2048;
    #pragma unroll
    for (int j = 0; j < 4; ++j) {
        float ej = 0.f;
        #pragma unroll
        for (int i = 0; i < 4; ++i)
            #pragma unroll
            for (int r = 0; r < 4; ++r) ej += __expf(acc[i][j][r]);
        ej += __shfl_xor(ej, 16, 64);
        ej += __shfl_xor(ej, 32, 64);
        if (quad == 0)
            atomicAdd(&sc[tileN + wn + j * 16 + l16], ej);
    }
}

// ---------------------------------------------------------------------------
// Fused scores+softmax+PV.  Grid 512 linear = 8 XCD x (32 qt x 2 hi).
// Block 256 (4 waves); per block q rows [qt*64,+64), head h.
// qh fragments loop-invariant in 64 VGPR (loaded once from global).
// Loop 64 key-tiles of 32: stage(t+1) -> S^T(t)=kh@bq -> p=exp(s)*rcp(sum)
// -> NT attn write + p16 pack -> barrier -> PV(t).
// kh dbuf, vh TRIPLE buf (read post-barrier), p16 dbuf: race-free, 1 barrier
// per tile.  LDS 48KB.
// ---------------------------------------------------------------------------
__global__ __launch_bounds__(256, 2)
void fused_pv(const unsigned short* __restrict__ qh,
              const unsigned short* __restrict__ kh,
              const unsigned short* __restrict__ vhT,
              const float* __restrict__ sums,
              float* __restrict__ attn, unsigned short* __restrict__ O)
{
    __shared__ unsigned short kh_s[2][32 * 128];
    __shared__ unsigned short vh_s[3][128 * 32];
    __shared__ unsigned short p16[2][64 * 32];

    const int tid = threadIdx.x;
    const int wave = tid >> 6, lane = tid & 63, quad = lane >> 4, l16 = lane & 15;
    const int slot = blockIdx.x >> 3;
    const int qt = slot & 31;
    const int h  = (blockIdx.x & 7) + 8 * (slot >> 5);
    const int wA = wave >> 1, wB = wave & 1;   // S:  wA=key-half(16), wB=q-half(32)
                                               // PV: wA=q-half(32),   wB=vd-half(64)
    const unsigned short* qg = qh + (long long)h * 262144 + (long long)qt * 64 * 128;
    const unsigned short* kg = kh + (long long)h * 262144;
    const unsigned short* vg = vhT + (long long)h * 262144;
    const float* smp = sums + h * 2048;
    float* ap = attn + (long long)h * L * L + (long long)qt * 64 * 2048;

    auto stage_kv = [&](int kt, int kb_, int vb_) {
        #pragma unroll
        for (int jj = 0; jj < 2; ++jj) {       // kh tile: 32 rows x 128 dk = 512 chunks
            const int c = tid + jj * 256;
            const int rl = c >> 4, sl = (c & 15) ^ (rl & 7);
            gload_lds16(kg + (long long)(kt * 32 + rl) * 128 + sl * 8, &kh_s[kb_][c * 8]);
        }
        #pragma unroll
        for (int jj = 0; jj < 2; ++jj) {       // vh tile: 128 vd x 32 keys = 512 chunks
            const int c = tid + jj * 256;
            const int vd = c >> 2, sl = (c & 3) ^ (vd & 3);
            gload_lds16(vg + (long long)vd * 2048 + kt * 32 + sl * 8, &vh_s[vb_][c * 8]);
        }
    };

    // prologue: qh fragments straight into registers (loop-invariant).
    // bq[j][g] covers q = wB*32+j*16+l16, dk = g*32+quad*8..+8.
    bf16x8 bq[2][4];
    #pragma unroll
    for (int j = 0; j < 2; ++j) {
        const int q = wB * 32 + j * 16 + l16;
        #pragma unroll
        for (int g = 0; g < 4; ++g)
            bq[j][g] = *(const bf16x8*)(qg + (long long)q * 128 + g * 32 + quad * 8);
    }
    stage_kv(0, 0, 0);
    __syncthreads();

    f32x4 acc_o[2][4] = {};
    const int krow = wA * 16 + l16;            // S A-operand row (key, local)

    for (int t = 0; t < 64; ++t) {
        const int cb = t & 1;
        const int vb3 = t % 3;
        if (t < 63) stage_kv(t + 1, cb ^ 1, (t + 1) % 3);

        // prefetch this tile's key exp-sums (L2-hot 128KB table)
        const int kb = t * 32 + wA * 16 + quad * 4;
        const f32x4 sg4 = *(const f32x4*)(smp + kb);

        // S^T(t): A=kh (M=key 32), B=bq regs.  8 MFMA/wave.
        bf16x8 af[4];
        #pragma unroll
        for (int g = 0; g < 4; ++g)
            af[g] = *(const bf16x8*)(&kh_s[cb][krow * 128 + ((g * 32 + quad * 8) ^ ((krow & 7) << 3))]);
        f32x4 acc_s[2];
        __builtin_amdgcn_s_setprio(1);
        #pragma unroll
        for (int j = 0; j < 2; ++j) {
            f32x4 s = {};
            #pragma unroll
            for (int g = 0; g < 4; ++g)
                s = __builtin_amdgcn_mfma_f32_16x16x32_bf16(af[g], bq[j][g], s, 0, 0, 0);
            acc_s[j] = s;
        }
        __builtin_amdgcn_s_setprio(0);

        // normalize (p = exp(s) * 1/sum) + NT attn write + p16 pack.
        // D: row(key)=quad*4+r, col(q)=l16.
        f32x4 il4;
        #pragma unroll
        for (int r = 0; r < 4; ++r) il4[r] = __builtin_amdgcn_rcpf(sg4[r]);
        #pragma unroll
        for (int j = 0; j < 2; ++j) {
            const int q = wB * 32 + j * 16 + l16;
            f32x4 p;
            #pragma unroll
            for (int r = 0; r < 4; ++r)
                p[r] = __expf(acc_s[j][r]) * il4[r];
            __builtin_nontemporal_store(p, (f32x4*)(ap + (long long)q * 2048 + kb));
            s16x4 pk;
            #pragma unroll
            for (int r = 0; r < 4; ++r) pk[r] = (short)f2bf(p[r]);
            *(s16x4*)(&p16[cb][q * 32 + ((wA * 16 + quad * 4) ^ ((q & 3) << 3))]) = pk;
        }

        __syncthreads();   // p16(t) visible; stage(t+1) drained; S reads done

        // PV(t): P (64q x 32k) @ vh^T.  8 MFMA/wave.
        bf16x8 pa[2], vb[4];
        #pragma unroll
        for (int i = 0; i < 2; ++i) {
            const int qq = wA * 32 + i * 16 + l16;
            pa[i] = *(const bf16x8*)(&p16[cb][qq * 32 + ((quad * 8) ^ ((qq & 3) << 3))]);
        }
        #pragma unroll
        for (int j = 0; j < 4; ++j) {
            const int vd = wB * 64 + j * 16 + l16;
            vb[j] = *(const bf16x8*)(&vh_s[vb3][vd * 32 + ((quad * 8) ^ ((vd & 3) << 3))]);
        }
        __builtin_amdgcn_s_setprio(1);
        #pragma unroll
        for (int i = 0; i < 2; ++i)
            #pragma unroll
            for (int j = 0; j < 4; ++j)
                acc_o[i][j] = __builtin_amdgcn_mfma_f32_16x16x32_bf16(pa[i], vb[j], acc_o[i][j], 0, 0, 0);
        __builtin_amdgcn_s_setprio(0);
    }

    // O epilogue: O[q][h*128+vd] bf16.  D: row(q)=quad*4+r, col(vd)=l16.
    #pragma unroll
    for (int i = 0; i < 2; ++i) {
        const int q = qt * 64 + wA * 32 + i * 16 + quad * 4;
        #pragma unroll
        for (int j = 0; j < 4; ++j) {
            const int vd = h * 128 + wB * 64 + j * 16 + l16;
            #pragma unroll
            for (int r = 0; r < 4; ++r)
                O[(long long)(q + r) * 2048 + vd] = f2bf(acc_o[i][j][r]);
        }
    }
}

// ---------------------------------------------------------------------------
// prep: merged stage-0 (3 launches -> 1).  Flat grid 18464 x 256:
//   [0, 6144):       q,k,v fp32 -> bf16  (z = bid/2048, 8 elems/thread)
//   [6144, 18432):   Wq/Wk/Wv transpose+cvt (48 heads x 4x64 32-tiles)
//   [18432, 18464):  zero the exp-sums table (32K floats)
// ---------------------------------------------------------------------------
__global__ __launch_bounds__(256)
void prep(const float* __restrict__ q, const float* __restrict__ k,
          const float* __restrict__ v,
          const float* __restrict__ Wq, const float* __restrict__ Wk,
          const float* __restrict__ Wv,
          unsigned short* __restrict__ qkvb, unsigned short* __restrict__ WT,
          float* __restrict__ sums)
{
    __shared__ float t[32][33];
    const int bid = blockIdx.x;
    const int tid = threadIdx.x;

    if (bid < 6144) {                      // ---- cvt q,k,v ----
        const int z = bid >> 11, xb = bid & 2047;
        const float* in = z == 0 ? q : z == 1 ? k : v;
        const long long i = ((long long)xb * 256 + tid) * 8;
        const float4 f0 = *(const float4*)(in + i);
        const float4 f1 = *(const float4*)(in + i + 4);
        union { int4 v4; unsigned short u[8]; } tt;
        tt.u[0] = f2bf(f0.x); tt.u[1] = f2bf(f0.y); tt.u[2] = f2bf(f0.z); tt.u[3] = f2bf(f0.w);
        tt.u[4] = f2bf(f1.x); tt.u[5] = f2bf(f1.y); tt.u[6] = f2bf(f1.z); tt.u[7] = f2bf(f1.w);
        *(int4*)(qkvb + (long long)z * 4194304 + i) = tt.v4;
    } else if (bid < 18432) {              // ---- weight transpose ----
        const int r = bid - 6144;
        const int z = r >> 8, rr = r & 255;
        const int bx = rr & 3, by = rr >> 2;
        const int widx = z >> 4, hh = z & 15;
        const float* in = (widx == 0 ? Wq : widx == 1 ? Wk : Wv) + (long long)hh * 2048 * 128;
        unsigned short* o = WT + (long long)z * 262144;
        const int c0 = bx * 32, r0 = by * 32;
        const int tx = tid & 31, ty0 = tid >> 5;
        #pragma unroll
        for (int jj = 0; jj < 4; ++jj) {
            const int j = ty0 + jj * 8;
            t[j][tx] = in[(long long)(r0 + j) * 128 + (c0 + tx)];
        }
        __syncthreads();
        #pragma unroll
        for (int jj = 0; jj < 4; ++jj) {
            const int j = ty0 + jj * 8;
            o[(long long)(c0 + j) * 2048 + (r0 + tx)] = f2bf(t[tx][j]);
        }
    } else {                               // ---- zero sums ----
        const int bt = bid - 18432;
        float4 zz = {0.f, 0.f, 0.f, 0.f};
        ((float4*)sums)[bt * 256 + tid] = zz;
    }
}

// ---------------------------------------------------------------------------
// 32x32 tile transpose, fp32 in -> bf16 out. Block (32,8).  (Pw only.)
// ---------------------------------------------------------------------------
__global__ __launch_bounds__(256)
void transpose_f2b(const float* __restrict__ in, unsigned short* __restrict__ out,
                   int rows, int cols)
{
    __shared__ float t[32][33];
    const long long base = (long long)blockIdx.z * rows * cols;
    const int c0 = blockIdx.x * 32, r0 = blockIdx.y * 32;
    const int tx = threadIdx.x, ty0 = threadIdx.y;
    #pragma unroll
    for (int jj = 0; jj < 4; ++jj) {
        const int j = ty0 + jj * 8;
        t[j][tx] = in[base + (long long)(r0 + j) * cols + (c0 + tx)];
    }
    __syncthreads();
    #pragma unroll
    for (int jj = 0; jj < 4; ++jj) {
        const int j = ty0 + jj * 8;
        out[base + (long long)(c0 + j) * rows + (r0 + tx)] = f2bf(t[tx][j]);
    }
}

// ---------------------------------------------------------------------------
// Residual + bias + LayerNorm (all fp32), one block (256 thr) per row of 2048.
// float4 loads/stores (G13).
// ---------------------------------------------------------------------------
__global__ __launch_bounds__(256)
void ln_resid(const float* __restrict__ ypre, const float* __restrict__ resid,
              const float* __restrict__ pb, const float* __restrict__ g,
              const float* __restrict__ bta, float* __restrict__ y)
{
    __shared__ float as_[4], as2_[4];
    const int l = blockIdx.x;
    const int tid = threadIdx.x;
    const float4* yp4 = (const float4*)(ypre + (long long)l * DMODEL);
    const float4* rd4 = (const float4*)(resid + (long long)l * DMODEL);
    const float4* pb4 = (const float4*)pb;

    float4 v[2]; float s = 0.f, s2 = 0.f;
    #pragma unroll
    for (int i = 0; i < 2; ++i) {
        const int d = tid + i * 256;
        const float4 a = yp4[d], b = rd4[d], c = pb4[d];
        float4 t;
        t.x = a.x + c.x + b.x;  t.y = a.y + c.y + b.y;
        t.z = a.z + c.z + b.z;  t.w = a.w + c.w + b.w;
        v[i] = t;
        s  += t.x + t.y + t.z + t.w;
        s2 += t.x * t.x + t.y * t.y + t.z * t.z + t.w * t.w;
    }
    #pragma unroll
    for (int off = 32; off > 0; off >>= 1) {
        s  += __shfl_down(s, off, 64);
        s2 += __shfl_down(s2, off, 64);
    }
    const int wave = tid >> 6, lane = tid & 63;
    if (lane == 0) { as_[wave] = s; as2_[wave] = s2; }
    __syncthreads();
    const float S  = as_[0] + as_[1] + as_[2] + as_[3];
    const float S2 = as2_[0] + as2_[1] + as2_[2] + as2_[3];
    const float mu  = S * (1.0f / DMODEL);
    const float var = S2 * (1.0f / DMODEL) - mu * mu;
    const float rs  = rsqrtf(var + 1e-5f);
    const float4* g4 = (const float4*)g;
    const float4* b4 = (const float4*)bta;
    float4* y4 = (float4*)(y + (long long)l * DMODEL);
    #pragma unroll
    for (int i = 0; i < 2; ++i) {
        const int d = tid + i * 256;
        const float4 gg = g4[d], bb = b4[d], t = v[i];
        float4 o;
        o.x = (t.x - mu) * rs * gg.x + bb.x;  o.y = (t.y - mu) * rs * gg.y + bb.y;
        o.z = (t.z - mu) * rs * gg.z + bb.z;  o.w = (t.w - mu) * rs * gg.w + bb.w;
        y4[d] = o;
    }
}

// ---------------------------------------------------------------------------
extern "C" void kernel_launch(void* const* d_in, const int* in_sizes, int n_in,
                              void* d_out, int out_size, void* d_ws, size_t ws_size,
                              hipStream_t stream)
{
    const float* q  = (const float*)d_in[0];
    const float* k  = (const float*)d_in[1];
    const float* v  = (const float*)d_in[2];
    const float* Wq = (const float*)d_in[3];
    const float* Wk = (const float*)d_in[4];
    const float* Wv = (const float*)d_in[5];
    const float* Pw = (const float*)d_in[6];
    const float* Pb = (const float*)d_in[7];
    const float* Lg = (const float*)d_in[8];
    const float* Lb = (const float*)d_in[9];

    float* y    = (float*)d_out;
    float* attn = y + (size_t)L * DMODEL;               // output 1 (fp32), 268 MB

    // ws layout (bf16 elems), 40 MB:
    //   T0 [0,8MB): sums (128KB fp32) during attention, then Pw^T (8MB) for
    //               the proj GEMM (strictly after fused).
    //   qh [8,16), kh [16,24), vhT [24,32), O [32,40)
    //   ypre fp32 overlays qh+kh (dead after fused).
    // attn output region (268MB) is dead until fused writes it, so bf16
    // q,k,v (24MB) + Wq/Wk/Wv^T (24MB) are stashed there first.
    const size_t SEG = (size_t)4194304;
    unsigned short* T0  = (unsigned short*)d_ws;
    unsigned short* qh  = T0 + SEG;
    unsigned short* kh  = qh + SEG;
    unsigned short* vhT = kh + SEG;
    unsigned short* O   = vhT + SEG;
    float* ypre  = (float*)qh;
    float* sums  = (float*)d_ws;                        // [16][2048] fp32 = 128KB

    unsigned short* qkvb = (unsigned short*)attn;       // qb,kb,vb: 3 x SEG
    unsigned short* WT   = qkvb + 3 * SEG;              // WqT,WkT,WvT: 48 x 262144

    const float inv_temper = 0.022097086912079608f;     // 1/sqrt(2048)
    dim3 tb(32, 8);

    // Stage 0: merged cvt + weight transpose + sums zero (one launch).
    prep<<<dim3(18464), 256, 0, stream>>>(q, k, v, Wq, Wk, Wv, qkvb, WT, sums);

    // Stage 1: fused Q/K/V projections, 768 blocks, z -> XCD z&7 (SWZ=1).
    // BK=32: 32KB LDS -> 3 blocks/CU (MW=3); grid 768 = exactly 3/CU.
    gemm_bt<3, 128, 32, 1, 3><<<dim3(768), 256, 0, stream>>>(qkvb, WT, qh,
        2048, 2048, 2048, 0, 4194304LL, 262144LL, 262144LL, inv_temper);

    // Stage 2: stats — single-shot K=128 tiles, atomicAdd column exp-sums.
    stats_qk<<<dim3(4096), 256, 0, stream>>>(qh, kh, sums);

    // Stage 3: fused recompute-S + normalize + NT attn write + PV.
    fused_pv<<<dim3(512), 256, 0, stream>>>(qh, kh, vhT, sums, attn, O);

    // Stage 4: ypre = O @ proj_w.  512 blocks, B-panel -> XCD bx&7 (SWZ=3).
    // BM=64/BK=64: 48KB LDS -> 3 blocks/CU with MW=3.
    transpose_f2b<<<dim3(64, 64, 1), tb, 0, stream>>>(Pw, T0, 2048, 2048);
    gemm_bt<2, 64, 64, 3, 3><<<dim3(512), 256, 0, stream>>>(O, T0, (void*)ypre,
        2048, 2048, 2048, 2048, 0LL, 0LL, 0LL, 1.0f);

    // Stage 5: y = LayerNorm(ypre + proj_b + residual) * g + b
    ln_resid<<<dim3(2048), 256, 0, stream>>>(ypre, q, Pb, Lg, Lb, y);
}